// Round 2
// baseline (451.064 us; speedup 1.0000x reference)
//
#include <hip/hip_runtime.h>
#include <cstddef>
#include <cstdint>

#define B_    8
#define CIN_  256
#define COUT_ 256
#define K_    4
#define H_    128
#define W_    128
#define HW_   (H_ * W_)    // 16384
#define P_    (B_ * HW_)   // 131072
#define BN_EPS 1e-5f

typedef __attribute__((ext_vector_type(8))) short bf16x8_t;   // 8 bf16 payloads (4 VGPRs)
typedef __attribute__((ext_vector_type(4))) float f32x4_t;

// fp32 -> bf16 payload, round-to-nearest-even
__device__ __forceinline__ unsigned short f2bf(float f) {
    unsigned int u = __float_as_uint(f);
    u += 0x7fffu + ((u >> 16) & 1u);
    return (unsigned short)(u >> 16);
}
// uint holding 2 bf16 -> float2 (2 VALU ops)
__device__ __forceinline__ float2 up2(unsigned int u) {
    return make_float2(__uint_as_float(u << 16), __uint_as_float(u & 0xffff0000u));
}
__device__ __forceinline__ void fma2(float2& d, float s, float2 v) {
    d.x = fmaf(s, v.x, d.x);
    d.y = fmaf(s, v.y, d.y);
}

// async global->LDS, 16B per lane; lds base must be wave-uniform (HW adds lane*16)
#define GL2LDS(g, l)                                                                     \
    __builtin_amdgcn_global_load_lds((const __attribute__((address_space(1))) void*)(g), \
                                     (__attribute__((address_space(3))) void*)(l), 16, 0, 0)

// ---------------------------------------------------------------------------
// K0: prep. Blocks 0..63: cast conv_w to bf16. Block 64: fold BN into out_w:
//   wB'[n][c] = bf16(out_w[n][c] * inv[c]),  inv = gamma/sqrt(var+eps)
//   bias'[n]  = out_b[n] + sum_c (beta[c] - mean[c]*inv[c]) * out_w[n][c]
// ---------------------------------------------------------------------------
__global__ __launch_bounds__(256) void k_prep(
    const float* __restrict__ conv_w, const float* __restrict__ out_w,
    const float* __restrict__ gamma, const float* __restrict__ beta,
    const float* __restrict__ rmean, const float* __restrict__ rvar,
    const float* __restrict__ out_b,
    unsigned short* __restrict__ wA, unsigned short* __restrict__ wB,
    float* __restrict__ bias2)
{
    const int t = threadIdx.x;
    if (blockIdx.x < 64) {
        const int i = (blockIdx.x * 256 + t) * 4;
        float4 a = *(const float4*)&conv_w[i];
        uint2 pa;
        pa.x = (unsigned)f2bf(a.x) | ((unsigned)f2bf(a.y) << 16);
        pa.y = (unsigned)f2bf(a.z) | ((unsigned)f2bf(a.w) << 16);
        *(uint2*)&wA[i] = pa;
    } else {
        __shared__ float sinv[256], sd[256];
        const float iv = gamma[t] * rsqrtf(rvar[t] + BN_EPS);
        sinv[t] = iv;
        sd[t]   = beta[t] - rmean[t] * iv;
        __syncthreads();
        float acc = out_b[t];
        for (int c = 0; c < 256; c += 4) {
            const float4 wv = *(const float4*)&out_w[t * 256 + c];
            acc += sd[c] * wv.x + sd[c + 1] * wv.y + sd[c + 2] * wv.z + sd[c + 3] * wv.w;
            uint2 p;
            p.x = (unsigned)f2bf(wv.x * sinv[c])     | ((unsigned)f2bf(wv.y * sinv[c + 1]) << 16);
            p.y = (unsigned)f2bf(wv.z * sinv[c + 2]) | ((unsigned)f2bf(wv.w * sinv[c + 3]) << 16);
            *(uint2*)&wB[t * 256 + c] = p;
        }
        bias2[t] = acc;
    }
}

// ---------------------------------------------------------------------------
// K1: flows + softmax + bilinear table + pixel-major bf16 x^T.
// v4: WIDE LOADS. Thread owns a 4-pixel quad; x read as float4 (16B/lane,
// 1 KiB/wave-instr contiguous -- the measured-6.3TB/s pattern). 4 waves split
// channels (16/chunk each); partial 12-dot-products reduced via pitch-49 LDS.
// xT written as uint4 (16B) per (px, 8ch); the 512B pixel row is completed by
// 4 waves x 4 chunks x 2 halves of the same block (L2 merges; round-1 showed
// no write amplification for the same assembly pattern).
// ---------------------------------------------------------------------------
__global__ __launch_bounds__(256) void k_flows(
    const float* __restrict__ x, const float* __restrict__ off_w,
    const float* __restrict__ off_b, const float* __restrict__ wgt_w,
    const float* __restrict__ wgt_b, unsigned short* __restrict__ xT,
    float4* __restrict__ tabW, int4* __restrict__ tabI)
{
    // phase 1: first 3072 floats hold coef[j][c]; phase 2: red[4][64][49]
    __shared__ float smem[4 * 64 * 49];            // 50176 B
    const int t = threadIdx.x;
    for (int idx = t; idx < 12 * 256; idx += 256)
        smem[idx] = (idx < 8 * 256) ? off_w[idx] : wgt_w[idx - 8 * 256];
    __syncthreads();

    const int q  = t & 63;                  // pixel-quad id within block
    const int g  = t >> 6;                  // wave id = channel-strip owner
    const int px0 = blockIdx.x * 256;       // 256 | 16384: whole block same b
    const int p4 = px0 + q * 4;             // this thread's 4 pixels
    const int b  = p4 >> 14;
    const float* xq = x + (size_t)b * (256 * HW_) + (p4 & (HW_ - 1));

    float acc[12][4];
#pragma unroll
    for (int j = 0; j < 12; ++j)
#pragma unroll
        for (int o = 0; o < 4; ++o) acc[j][o] = 0.f;

#pragma unroll
    for (int chunk = 0; chunk < 4; ++chunk) {
        const int cbase = chunk * 64 + g * 16;     // this wave's 16-ch strip
#pragma unroll
        for (int bb = 0; bb < 2; ++bb) {           // 8 channels per half
            float4 f4[8];
#pragma unroll
            for (int i = 0; i < 8; ++i)
                f4[i] = *(const float4*)&xq[(size_t)(cbase + bb * 8 + i) * HW_];
#pragma unroll
            for (int i = 0; i < 8; ++i) {
                const int ch = cbase + bb * 8 + i;
#pragma unroll
                for (int j = 0; j < 12; ++j) {
                    const float cw = smem[j * 256 + ch];   // LDS broadcast
                    acc[j][0] = fmaf(f4[i].x, cw, acc[j][0]);
                    acc[j][1] = fmaf(f4[i].y, cw, acc[j][1]);
                    acc[j][2] = fmaf(f4[i].z, cw, acc[j][2]);
                    acc[j][3] = fmaf(f4[i].w, cw, acc[j][3]);
                }
            }
            // pack+store: per pixel o, 8 ch bf16 = one uint4 (16B)
#pragma unroll
            for (int o = 0; o < 4; ++o) {
                const float vo[8] = {f4[0].x, f4[1].x, f4[2].x, f4[3].x,
                                     f4[4].x, f4[5].x, f4[6].x, f4[7].x};
                float v[8];
#pragma unroll
                for (int i = 0; i < 8; ++i)
                    v[i] = (o == 0) ? f4[i].x : (o == 1) ? f4[i].y : (o == 2) ? f4[i].z : f4[i].w;
                (void)vo;
                uint4 u;
                u.x = (unsigned)f2bf(v[0]) | ((unsigned)f2bf(v[1]) << 16);
                u.y = (unsigned)f2bf(v[2]) | ((unsigned)f2bf(v[3]) << 16);
                u.z = (unsigned)f2bf(v[4]) | ((unsigned)f2bf(v[5]) << 16);
                u.w = (unsigned)f2bf(v[6]) | ((unsigned)f2bf(v[7]) << 16);
                *(uint4*)&xT[(size_t)(p4 + o) * 256 + cbase + bb * 8] = u;
            }
        }
    }

    __syncthreads();                  // coef dead; reuse smem as red[4][64][49]
#pragma unroll
    for (int j = 0; j < 12; ++j)
#pragma unroll
        for (int o = 0; o < 4; ++o)
            smem[(g * 64 + q) * 49 + j * 4 + o] = acc[j][o];
    __syncthreads();

    {
        const int q2 = t >> 2, o2 = t & 3;
        const int p  = px0 + t;              // == px0 + 4*q2 + o2: coalesced tabs
        float a[12];
#pragma unroll
        for (int j = 0; j < 12; ++j)
            a[j] = (smem[(0 * 64 + q2) * 49 + j * 4 + o2] + smem[(1 * 64 + q2) * 49 + j * 4 + o2])
                 + (smem[(2 * 64 + q2) * 49 + j * 4 + o2] + smem[(3 * 64 + q2) * 49 + j * 4 + o2]);

        const int hw = p & (HW_ - 1);
        const int w = hw & (W_ - 1);
        const int h = hw >> 7;
        float l[4];
#pragma unroll
        for (int k = 0; k < 4; ++k) l[k] = a[8 + k] + wgt_b[k];
        const float m  = fmaxf(fmaxf(l[0], l[1]), fmaxf(l[2], l[3]));
        const float e0 = __expf(l[0] - m), e1 = __expf(l[1] - m);
        const float e2 = __expf(l[2] - m), e3 = __expf(l[3] - m);
        const float sinv = 1.f / (e0 + e1 + e2 + e3);
        float wk[4] = {e0 * sinv, e1 * sinv, e2 * sinv, e3 * sinv};

#pragma unroll
        for (int k = 0; k < 4; ++k) {
            const float sx = (float)w + a[k * 2 + 0] + off_b[k * 2 + 0];  // unnorm(norm(.)) == id
            const float sy = (float)h + a[k * 2 + 1] + off_b[k * 2 + 1];
            const float x0f = floorf(sx), y0f = floorf(sy);
            const float fx = sx - x0f, fy = sy - y0f;
            const float vx0 = (x0f >= 0.f  && x0f <= (float)(W_ - 1)) ? 1.f : 0.f;
            const float vx1 = (x0f >= -1.f && x0f <= (float)(W_ - 2)) ? 1.f : 0.f;
            const float vy0 = (y0f >= 0.f  && y0f <= (float)(H_ - 1)) ? 1.f : 0.f;
            const float vy1 = (y0f >= -1.f && y0f <= (float)(H_ - 2)) ? 1.f : 0.f;
            const int x0 = (int)x0f, y0 = (int)y0f;
            const int cx0 = min(max(x0, 0), W_ - 1);
            const int cx1 = min(max(x0 + 1, 0), W_ - 1);
            const int cy0 = min(max(y0, 0), H_ - 1);
            const int cy1 = min(max(y0 + 1, 0), H_ - 1);
            float4 wv;
            wv.x = (1.f - fx) * (1.f - fy) * wk[k] * vx0 * vy0;
            wv.y = fx * (1.f - fy) * wk[k] * vx1 * vy0;
            wv.z = (1.f - fx) * fy * wk[k] * vx0 * vy1;
            wv.w = fx * fy * wk[k] * vx1 * vy1;
            int4 ov;
            ov.x = (cy0 * W_ + cx0) * 256;
            ov.y = (cy0 * W_ + cx1) * 256;
            ov.z = (cy1 * W_ + cx0) * 256;
            ov.w = (cy1 * W_ + cx1) * 256;
            tabW[(size_t)k * P_ + p] = wv;
            tabI[(size_t)k * P_ + p] = ov;
        }
    }
}

// ---------------------------------------------------------------------------
// GEMM core (shared by k_proj / k_out): C[m=px][n=o] = sum_c A[px][c]*W[o][c]
// 128x128 tile, BK=64, fragment-major LDS staged via global_load_lds(16B).
// ---------------------------------------------------------------------------
#define GEMM_STAGE_AND_MFMA(A_, W_ptr_, smem_)                                              \
    char* As = smem_;                                                                       \
    char* Bs = smem_ + 16384;                                                               \
    const int w  = t >> 6;                                                                  \
    const int l  = t & 63;                                                                  \
    const int lr = l & 15;                                                                  \
    const int lq = l >> 4;                                                                  \
    f32x4_t acc[4][4];                                                                      \
    _Pragma("unroll") for (int i = 0; i < 4; ++i)                                           \
        _Pragma("unroll") for (int j = 0; j < 4; ++j)                                       \
            acc[i][j] = (f32x4_t){0.f, 0.f, 0.f, 0.f};                                      \
    const int wm = (w & 1) * 4;                                                             \
    const int wn = (w >> 1) * 4;                                                            \
    _Pragma("unroll") for (int ks = 0; ks < 4; ++ks) {                                      \
        const int k0 = ks * 64;                                                             \
        __syncthreads();                                                                    \
        _Pragma("unroll") for (int i = 0; i < 2; ++i) {                                     \
            const int mt = 2 * w + i;                                                       \
            _Pragma("unroll") for (int kc = 0; kc < 2; ++kc) {                              \
                const unsigned short* g =                                                   \
                    A_ + (size_t)(p0 + mt * 16 + lr) * 256 + k0 + kc * 32 + lq * 8;         \
                GL2LDS(g, As + (kc * 8 + mt) * 1024);                                       \
            }                                                                               \
        }                                                                                   \
        _Pragma("unroll") for (int i = 0; i < 2; ++i) {                                     \
            const int nt = 2 * w + i;                                                       \
            _Pragma("unroll") for (int kc = 0; kc < 2; ++kc) {                              \
                const unsigned short* g =                                                   \
                    W_ptr_ + (size_t)(n0 + nt * 16 + lr) * 256 + k0 + kc * 32 + lq * 8;     \
                GL2LDS(g, Bs + (kc * 8 + nt) * 1024);                                       \
            }                                                                               \
        }                                                                                   \
        __syncthreads();                                                                    \
        _Pragma("unroll") for (int kc = 0; kc < 2; ++kc) {                                  \
            bf16x8_t af[4], bfr[4];                                                         \
            _Pragma("unroll") for (int i = 0; i < 4; ++i)                                   \
                af[i] = *(const bf16x8_t*)(As + (kc * 8 + wm + i) * 1024 + l * 16);         \
            _Pragma("unroll") for (int j = 0; j < 4; ++j)                                   \
                bfr[j] = *(const bf16x8_t*)(Bs + (kc * 8 + wn + j) * 1024 + l * 16);        \
            _Pragma("unroll") for (int i = 0; i < 4; ++i)                                   \
                _Pragma("unroll") for (int j = 0; j < 4; ++j)                               \
                    acc[i][j] =                                                             \
                        __builtin_amdgcn_mfma_f32_16x16x32_bf16(af[i], bfr[j], acc[i][j],   \
                                                                0, 0, 0);                   \
        }                                                                                   \
    }

// K2: proj = xT . conv_w^T + conv_b -> bf16 pixel-major [p][o]
__global__ __launch_bounds__(256, 3) void k_proj(
    const unsigned short* __restrict__ A, const unsigned short* __restrict__ Wb,
    const float* __restrict__ bias, unsigned short* __restrict__ Cout)
{
    __shared__ alignas(16) char smem[33792];
    const int t  = threadIdx.x;
    const int bx = blockIdx.x;
    const int n0 = (bx & 1) * 128;
    const int p0 = (bx >> 1) * 128;

    GEMM_STAGE_AND_MFMA(A, Wb, smem)

    __syncthreads();
    unsigned short* ep = (unsigned short*)smem;
    const int mh = (w & 1) * 64, nh = (w >> 1) * 64;
#pragma unroll
    for (int j = 0; j < 4; ++j) {
        const int   col = nh + j * 16 + lr;
        const float bv  = bias[n0 + col];
#pragma unroll
        for (int i = 0; i < 4; ++i) {
#pragma unroll
            for (int r = 0; r < 4; ++r) {
                const int row = mh + i * 16 + lq * 4 + r;
                ep[row * 132 + col] = f2bf(acc[i][j][r] + bv);
            }
        }
    }
    __syncthreads();
#pragma unroll
    for (int pass = 0; pass < 16; ++pass) {
        const int row = pass * 8 + (t >> 5);
        const int c4  = (t & 31) * 4;
        const uint2 v = *(const uint2*)&ep[row * 132 + c4];
        *(uint2*)&Cout[(size_t)(p0 + row) * 256 + n0 + c4] = v;
    }
}

// K4: out = feat . wB'^T + bias' -> fp32 channel-major [b][n][hw]
__global__ __launch_bounds__(256, 3) void k_out(
    const unsigned short* __restrict__ A, const unsigned short* __restrict__ Wb,
    const float* __restrict__ bias, float* __restrict__ Cout)
{
    __shared__ alignas(16) char smem[32768];
    const int t  = threadIdx.x;
    const int bx = blockIdx.x;
    const int n0 = (bx & 1) * 128;
    const int p0 = (bx >> 1) * 128;

    GEMM_STAGE_AND_MFMA(A, Wb, smem)

    const int mh = (w & 1) * 64, nh = (w >> 1) * 64;
    const int b   = p0 >> 14;
    const int hw0 = p0 & (HW_ - 1);
#pragma unroll
    for (int j = 0; j < 4; ++j) {
        const int   n  = n0 + nh + j * 16 + lr;
        const float bb = bias[n];
#pragma unroll
        for (int i = 0; i < 4; ++i) {
            f32x4_t v = acc[i][j];
            v[0] += bb; v[1] += bb; v[2] += bb; v[3] += bb;
            *(f32x4_t*)&Cout[(size_t)(b * 256 + n) * HW_ + hw0 + mh + i * 16 + lq * 4] = v;
        }
    }
}

// ---------------------------------------------------------------------------
// K3: gather + weighted sum + residual (BN folded into k_out weights).
// 8 channels/lane (uint4 = 16B gathers), 32 lanes per pixel, no coord math.
// ---------------------------------------------------------------------------
__global__ __launch_bounds__(256) void k_sample(
    const unsigned short* __restrict__ proj, const float4* __restrict__ tabW,
    const int4* __restrict__ tabI, unsigned short* __restrict__ feat)
{
    const int t  = threadIdx.x;
    const int w  = t >> 6;
    const int l  = t & 63;
    const int ph = l >> 5;
    const int c0 = (l & 31) * 8;

    const int pbase = blockIdx.x * 16;     // 16384 % 16 == 0: same b for whole block
    const int b = pbase >> 14;
    const unsigned short* projb = proj + (size_t)b * HW_ * 256;

#pragma unroll
    for (int it = 0; it < 2; ++it) {
        const int p = pbase + it * 8 + w * 2 + ph;
        const uint4 rv = *(const uint4*)&proj[(size_t)p * 256 + c0];
        float2 a0 = up2(rv.x), a1 = up2(rv.y), a2 = up2(rv.z), a3 = up2(rv.w);
#pragma unroll
        for (int k = 0; k < 4; ++k) {
            const float4 wv = tabW[(size_t)k * P_ + p];   // broadcast within half-wave
            const int4   ov = tabI[(size_t)k * P_ + p];
            const uint4 g0 = *(const uint4*)&projb[ov.x + c0];
            const uint4 g1 = *(const uint4*)&projb[ov.y + c0];
            const uint4 g2 = *(const uint4*)&projb[ov.z + c0];
            const uint4 g3 = *(const uint4*)&projb[ov.w + c0];
            fma2(a0, wv.x, up2(g0.x)); fma2(a1, wv.x, up2(g0.y));
            fma2(a2, wv.x, up2(g0.z)); fma2(a3, wv.x, up2(g0.w));
            fma2(a0, wv.y, up2(g1.x)); fma2(a1, wv.y, up2(g1.y));
            fma2(a2, wv.y, up2(g1.z)); fma2(a3, wv.y, up2(g1.w));
            fma2(a0, wv.z, up2(g2.x)); fma2(a1, wv.z, up2(g2.y));
            fma2(a2, wv.z, up2(g2.z)); fma2(a3, wv.z, up2(g2.w));
            fma2(a0, wv.w, up2(g3.x)); fma2(a1, wv.w, up2(g3.y));
            fma2(a2, wv.w, up2(g3.z)); fma2(a3, wv.w, up2(g3.w));
        }
        uint4 o;
        o.x = (unsigned)f2bf(a0.x) | ((unsigned)f2bf(a0.y) << 16);
        o.y = (unsigned)f2bf(a1.x) | ((unsigned)f2bf(a1.y) << 16);
        o.z = (unsigned)f2bf(a2.x) | ((unsigned)f2bf(a2.y) << 16);
        o.w = (unsigned)f2bf(a3.x) | ((unsigned)f2bf(a3.y) << 16);
        *(uint4*)&feat[(size_t)p * 256 + c0] = o;
    }
}

extern "C" void kernel_launch(void* const* d_in, const int* in_sizes, int n_in,
                              void* d_out, int out_size, void* d_ws, size_t ws_size,
                              hipStream_t stream)
{
    const float* x      = (const float*)d_in[0];
    const float* conv_w = (const float*)d_in[1];
    const float* conv_b = (const float*)d_in[2];
    const float* off_w  = (const float*)d_in[3];
    const float* off_b  = (const float*)d_in[4];
    const float* wgt_w  = (const float*)d_in[5];
    const float* wgt_b  = (const float*)d_in[6];
    const float* gamma  = (const float*)d_in[7];
    const float* beta   = (const float*)d_in[8];
    const float* rmean  = (const float*)d_in[9];
    const float* rvar   = (const float*)d_in[10];
    const float* out_w  = (const float*)d_in[11];
    const float* out_b  = (const float*)d_in[12];

    char* ws = (char*)d_ws;
    unsigned short* xT   = (unsigned short*)(ws);                      // 64 MiB
    unsigned short* proj = (unsigned short*)(ws + (size_t)67108864);   // 64 MiB
    unsigned short* feat = (unsigned short*)(ws + (size_t)134217728);  // 64 MiB
    float4*         tabW = (float4*)(ws + (size_t)201326592);          // 8 MiB
    int4*           tabI = (int4*)(ws + (size_t)209715200);            // 8 MiB
    unsigned short* wA   = (unsigned short*)(ws + (size_t)218103808);  // 128 KiB
    unsigned short* wB   = (unsigned short*)(ws + (size_t)218234880);  // 128 KiB
    float*          bias2= (float*)(ws + (size_t)218365952);           // 1 KiB

    k_prep  <<<65,         256, 0, stream>>>(conv_w, out_w, gamma, beta, rmean, rvar,
                                             out_b, wA, wB, bias2);
    k_flows <<<P_ / 256,   256, 0, stream>>>(x, off_w, off_b, wgt_w, wgt_b, xT, tabW, tabI);
    k_proj  <<<(P_/128)*2, 256, 0, stream>>>(xT, wA, conv_b, proj);
    k_sample<<<P_ / 16,    256, 0, stream>>>(proj, tabW, tabI, feat);
    k_out   <<<(P_/128)*2, 256, 0, stream>>>(feat, wB, bias2, (float*)d_out);
}

// Round 4
// 426.163 us; speedup vs baseline: 1.0584x; 1.0584x over previous
//
#include <hip/hip_runtime.h>
#include <cstddef>
#include <cstdint>

#define B_    8
#define CIN_  256
#define COUT_ 256
#define K_    4
#define H_    128
#define W_    128
#define HW_   (H_ * W_)    // 16384
#define P_    (B_ * HW_)   // 131072
#define BN_EPS 1e-5f

typedef __attribute__((ext_vector_type(8))) short bf16x8_t;   // 8 bf16 payloads (4 VGPRs)
typedef __attribute__((ext_vector_type(4))) float f32x4_t;

// fp32 -> bf16 payload, round-to-nearest-even
__device__ __forceinline__ unsigned short f2bf(float f) {
    unsigned int u = __float_as_uint(f);
    u += 0x7fffu + ((u >> 16) & 1u);
    return (unsigned short)(u >> 16);
}
// uint holding 2 bf16 -> float2 (2 VALU ops)
__device__ __forceinline__ float2 up2(unsigned int u) {
    return make_float2(__uint_as_float(u << 16), __uint_as_float(u & 0xffff0000u));
}
__device__ __forceinline__ void fma2(float2& d, float s, float2 v) {
    d.x = fmaf(s, v.x, d.x);
    d.y = fmaf(s, v.y, d.y);
}

// async global->LDS, 16B per lane; lds base must be wave-uniform (HW adds lane*16)
#define GL2LDS(g, l)                                                                     \
    __builtin_amdgcn_global_load_lds((const __attribute__((address_space(1))) void*)(g), \
                                     (__attribute__((address_space(3))) void*)(l), 16, 0, 0)

// ---------------------------------------------------------------------------
// K0: prep. Blocks 0..63: cast conv_w to bf16. Block 64: fold BN into out_w:
//   wB'[n][c] = bf16(out_w[n][c] * inv[c]),  inv = gamma/sqrt(var+eps)
//   bias'[n]  = out_b[n] + sum_c (beta[c] - mean[c]*inv[c]) * out_w[n][c]
// ---------------------------------------------------------------------------
__global__ __launch_bounds__(256) void k_prep(
    const float* __restrict__ conv_w, const float* __restrict__ out_w,
    const float* __restrict__ gamma, const float* __restrict__ beta,
    const float* __restrict__ rmean, const float* __restrict__ rvar,
    const float* __restrict__ out_b,
    unsigned short* __restrict__ wA, unsigned short* __restrict__ wB,
    float* __restrict__ bias2)
{
    const int t = threadIdx.x;
    if (blockIdx.x < 64) {
        const int i = (blockIdx.x * 256 + t) * 4;
        float4 a = *(const float4*)&conv_w[i];
        uint2 pa;
        pa.x = (unsigned)f2bf(a.x) | ((unsigned)f2bf(a.y) << 16);
        pa.y = (unsigned)f2bf(a.z) | ((unsigned)f2bf(a.w) << 16);
        *(uint2*)&wA[i] = pa;
    } else {
        __shared__ float sinv[256], sd[256];
        const float iv = gamma[t] * rsqrtf(rvar[t] + BN_EPS);
        sinv[t] = iv;
        sd[t]   = beta[t] - rmean[t] * iv;
        __syncthreads();
        float acc = out_b[t];
        for (int c = 0; c < 256; c += 4) {
            const float4 wv = *(const float4*)&out_w[t * 256 + c];
            acc += sd[c] * wv.x + sd[c + 1] * wv.y + sd[c + 2] * wv.z + sd[c + 3] * wv.w;
            uint2 p;
            p.x = (unsigned)f2bf(wv.x * sinv[c])     | ((unsigned)f2bf(wv.y * sinv[c + 1]) << 16);
            p.y = (unsigned)f2bf(wv.z * sinv[c + 2]) | ((unsigned)f2bf(wv.w * sinv[c + 3]) << 16);
            *(uint2*)&wB[t * 256 + c] = p;
        }
        bias2[t] = acc;
    }
}

// ---------------------------------------------------------------------------
// K1: flows + softmax + bilinear table + pixel-major bf16 x^T.
// v5: float4 reads (16B/lane, 1KB/wave-instr -- 4x fewer vmem instrs than
// dword) + per-chunk LDS transpose so every xT store wave-instr completes
// 8 FULL 128B lines (r2's 16B-scattered stores caused 2x write amplification:
// WRITE_SIZE 83->166MB). Thread = 4-px quad x 16-ch strip; FMAs in registers;
// 4-wave partial-sum reduction through conflict-free [j4o][256] smem layout.
// ---------------------------------------------------------------------------
__global__ __launch_bounds__(256) void k_flows(
    const float* __restrict__ x, const float* __restrict__ off_w,
    const float* __restrict__ off_b, const float* __restrict__ wgt_w,
    const float* __restrict__ wgt_b, unsigned short* __restrict__ xT,
    float4* __restrict__ tabW, int4* __restrict__ tabI)
{
    __shared__ alignas(16) char smem_raw[49152];
    float*          coef = (float*)smem_raw;                        // [12][256], 12 KB
    unsigned short* tile = (unsigned short*)(smem_raw + 12288);     // [256][72], 36 KB
    float*          red  = (float*)smem_raw;                        // [48][256], 48 KB (reuse)

    const int t = threadIdx.x;
    for (int idx = t; idx < 12 * 256; idx += 256)
        coef[idx] = (idx < 8 * 256) ? off_w[idx] : wgt_w[idx - 8 * 256];
    __syncthreads();

    const int q   = t & 63;                 // pixel-quad id within block
    const int g   = t >> 6;                 // wave id = 16-ch strip owner
    const int px0 = blockIdx.x * 256;       // 256 | 16384: whole block same b
    const int p4  = px0 + q * 4;
    const int b   = p4 >> 14;
    const float* xq = x + (size_t)b * (256 * HW_) + (p4 & (HW_ - 1));

    float acc[12][4];
#pragma unroll
    for (int j = 0; j < 12; ++j)
#pragma unroll
        for (int o = 0; o < 4; ++o) acc[j][o] = 0.f;

    for (int chunk = 0; chunk < 4; ++chunk) {
        const int cb = chunk * 64 + g * 16;
#pragma unroll
        for (int bb = 0; bb < 2; ++bb) {
            float4 f4[8];
#pragma unroll
            for (int i = 0; i < 8; ++i)
                f4[i] = *(const float4*)&xq[(size_t)(cb + bb * 8 + i) * HW_];
#pragma unroll
            for (int i = 0; i < 8; ++i) {
                const int ch = cb + bb * 8 + i;
#pragma unroll
                for (int j = 0; j < 12; ++j) {
                    const float cw = coef[j * 256 + ch];   // LDS broadcast
                    acc[j][0] = fmaf(f4[i].x, cw, acc[j][0]);
                    acc[j][1] = fmaf(f4[i].y, cw, acc[j][1]);
                    acc[j][2] = fmaf(f4[i].z, cw, acc[j][2]);
                    acc[j][3] = fmaf(f4[i].w, cw, acc[j][3]);
                }
            }
            // transpose-stage: per pixel o, 8 ch bf16 = one uint4 into LDS tile
#pragma unroll
            for (int o = 0; o < 4; ++o) {
                float v[8];
#pragma unroll
                for (int i = 0; i < 8; ++i)
                    v[i] = (o == 0) ? f4[i].x : (o == 1) ? f4[i].y : (o == 2) ? f4[i].z : f4[i].w;
                uint4 u;
                u.x = (unsigned)f2bf(v[0]) | ((unsigned)f2bf(v[1]) << 16);
                u.y = (unsigned)f2bf(v[2]) | ((unsigned)f2bf(v[3]) << 16);
                u.z = (unsigned)f2bf(v[4]) | ((unsigned)f2bf(v[5]) << 16);
                u.w = (unsigned)f2bf(v[6]) | ((unsigned)f2bf(v[7]) << 16);
                *(uint4*)&tile[(4 * q + o) * 72 + g * 16 + bb * 8] = u;
            }
        }
        __syncthreads();
        // write out: each wave-instr covers 8 px x full 128B line
        {
            const int row8 = t >> 3, lane8 = t & 7;
#pragma unroll
            for (int pass = 0; pass < 8; ++pass) {
                const int row = pass * 32 + row8;
                const uint4 v = *(const uint4*)&tile[row * 72 + lane8 * 8];
                *(uint4*)&xT[(size_t)(px0 + row) * 256 + chunk * 64 + lane8 * 8] = v;
            }
        }
        __syncthreads();
    }

    // 4-wave partial-sum reduction (coef+tile dead; reuse whole smem block)
#pragma unroll
    for (int j = 0; j < 12; ++j)
#pragma unroll
        for (int o = 0; o < 4; ++o)
            red[(j * 4 + o) * 256 + g * 64 + q] = acc[j][o];   // lanes stride 1: conflict-free
    __syncthreads();

    {
        const int p = px0 + t;               // q2 = t>>2, o2 = t&3: coalesced tabs
        float a[12];
#pragma unroll
        for (int j = 0; j < 12; ++j) {
            const int base = (j * 4 + (t & 3)) * 256 + (t >> 2);
            a[j] = (red[base] + red[base + 64]) + (red[base + 128] + red[base + 192]);
        }

        const int hw = p & (HW_ - 1);
        const int w = hw & (W_ - 1);
        const int h = hw >> 7;
        float l[4];
#pragma unroll
        for (int k = 0; k < 4; ++k) l[k] = a[8 + k] + wgt_b[k];
        const float m  = fmaxf(fmaxf(l[0], l[1]), fmaxf(l[2], l[3]));
        const float e0 = __expf(l[0] - m), e1 = __expf(l[1] - m);
        const float e2 = __expf(l[2] - m), e3 = __expf(l[3] - m);
        const float sinv = 1.f / (e0 + e1 + e2 + e3);
        float wk[4] = {e0 * sinv, e1 * sinv, e2 * sinv, e3 * sinv};

#pragma unroll
        for (int k = 0; k < 4; ++k) {
            const float sx = (float)w + a[k * 2 + 0] + off_b[k * 2 + 0];  // unnorm(norm(.)) == id
            const float sy = (float)h + a[k * 2 + 1] + off_b[k * 2 + 1];
            const float x0f = floorf(sx), y0f = floorf(sy);
            const float fx = sx - x0f, fy = sy - y0f;
            const float vx0 = (x0f >= 0.f  && x0f <= (float)(W_ - 1)) ? 1.f : 0.f;
            const float vx1 = (x0f >= -1.f && x0f <= (float)(W_ - 2)) ? 1.f : 0.f;
            const float vy0 = (y0f >= 0.f  && y0f <= (float)(H_ - 1)) ? 1.f : 0.f;
            const float vy1 = (y0f >= -1.f && y0f <= (float)(H_ - 2)) ? 1.f : 0.f;
            const int x0 = (int)x0f, y0 = (int)y0f;
            const int cx0 = min(max(x0, 0), W_ - 1);
            const int cx1 = min(max(x0 + 1, 0), W_ - 1);
            const int cy0 = min(max(y0, 0), H_ - 1);
            const int cy1 = min(max(y0 + 1, 0), H_ - 1);
            float4 wv;
            wv.x = (1.f - fx) * (1.f - fy) * wk[k] * vx0 * vy0;
            wv.y = fx * (1.f - fy) * wk[k] * vx1 * vy0;
            wv.z = (1.f - fx) * fy * wk[k] * vx0 * vy1;
            wv.w = fx * fy * wk[k] * vx1 * vy1;
            int4 ov;
            ov.x = (cy0 * W_ + cx0) * 256;
            ov.y = (cy0 * W_ + cx1) * 256;
            ov.z = (cy1 * W_ + cx0) * 256;
            ov.w = (cy1 * W_ + cx1) * 256;
            tabW[(size_t)k * P_ + p] = wv;
            tabI[(size_t)k * P_ + p] = ov;
        }
    }
}

// ---------------------------------------------------------------------------
// GEMM core (shared by k_proj / k_out): C[m=px][n=o] = sum_c A[px][c]*W[o][c]
// 128x128 tile, BK=64, fragment-major LDS staged via global_load_lds(16B).
// ---------------------------------------------------------------------------
#define GEMM_STAGE_AND_MFMA(A_, W_ptr_, smem_)                                              \
    char* As = smem_;                                                                       \
    char* Bs = smem_ + 16384;                                                               \
    const int w  = t >> 6;                                                                  \
    const int l  = t & 63;                                                                  \
    const int lr = l & 15;                                                                  \
    const int lq = l >> 4;                                                                  \
    f32x4_t acc[4][4];                                                                      \
    _Pragma("unroll") for (int i = 0; i < 4; ++i)                                           \
        _Pragma("unroll") for (int j = 0; j < 4; ++j)                                       \
            acc[i][j] = (f32x4_t){0.f, 0.f, 0.f, 0.f};                                      \
    const int wm = (w & 1) * 4;                                                             \
    const int wn = (w >> 1) * 4;                                                            \
    _Pragma("unroll") for (int ks = 0; ks < 4; ++ks) {                                      \
        const int k0 = ks * 64;                                                             \
        __syncthreads();                                                                    \
        _Pragma("unroll") for (int i = 0; i < 2; ++i) {                                     \
            const int mt = 2 * w + i;                                                       \
            _Pragma("unroll") for (int kc = 0; kc < 2; ++kc) {                              \
                const unsigned short* g =                                                   \
                    A_ + (size_t)(p0 + mt * 16 + lr) * 256 + k0 + kc * 32 + lq * 8;         \
                GL2LDS(g, As + (kc * 8 + mt) * 1024);                                       \
            }                                                                               \
        }                                                                                   \
        _Pragma("unroll") for (int i = 0; i < 2; ++i) {                                     \
            const int nt = 2 * w + i;                                                       \
            _Pragma("unroll") for (int kc = 0; kc < 2; ++kc) {                              \
                const unsigned short* g =                                                   \
                    W_ptr_ + (size_t)(n0 + nt * 16 + lr) * 256 + k0 + kc * 32 + lq * 8;     \
                GL2LDS(g, Bs + (kc * 8 + nt) * 1024);                                       \
            }                                                                               \
        }                                                                                   \
        __syncthreads();                                                                    \
        _Pragma("unroll") for (int kc = 0; kc < 2; ++kc) {                                  \
            bf16x8_t af[4], bfr[4];                                                         \
            _Pragma("unroll") for (int i = 0; i < 4; ++i)                                   \
                af[i] = *(const bf16x8_t*)(As + (kc * 8 + wm + i) * 1024 + l * 16);         \
            _Pragma("unroll") for (int j = 0; j < 4; ++j)                                   \
                bfr[j] = *(const bf16x8_t*)(Bs + (kc * 8 + wn + j) * 1024 + l * 16);        \
            _Pragma("unroll") for (int i = 0; i < 4; ++i)                                   \
                _Pragma("unroll") for (int j = 0; j < 4; ++j)                               \
                    acc[i][j] =                                                             \
                        __builtin_amdgcn_mfma_f32_16x16x32_bf16(af[i], bfr[j], acc[i][j],   \
                                                                0, 0, 0);                   \
        }                                                                                   \
    }

// K2: proj = xT . conv_w^T + conv_b -> bf16 pixel-major [p][o]
__global__ __launch_bounds__(256, 3) void k_proj(
    const unsigned short* __restrict__ A, const unsigned short* __restrict__ Wb,
    const float* __restrict__ bias, unsigned short* __restrict__ Cout)
{
    __shared__ alignas(16) char smem[33792];
    const int t  = threadIdx.x;
    const int bx = blockIdx.x;
    const int n0 = (bx & 1) * 128;
    const int p0 = (bx >> 1) * 128;

    GEMM_STAGE_AND_MFMA(A, Wb, smem)

    __syncthreads();
    unsigned short* ep = (unsigned short*)smem;
    const int mh = (w & 1) * 64, nh = (w >> 1) * 64;
#pragma unroll
    for (int j = 0; j < 4; ++j) {
        const int   col = nh + j * 16 + lr;
        const float bv  = bias[n0 + col];
#pragma unroll
        for (int i = 0; i < 4; ++i) {
#pragma unroll
            for (int r = 0; r < 4; ++r) {
                const int row = mh + i * 16 + lq * 4 + r;
                ep[row * 132 + col] = f2bf(acc[i][j][r] + bv);
            }
        }
    }
    __syncthreads();
#pragma unroll
    for (int pass = 0; pass < 16; ++pass) {
        const int row = pass * 8 + (t >> 5);
        const int c4  = (t & 31) * 4;
        const uint2 v = *(const uint2*)&ep[row * 132 + c4];
        *(uint2*)&Cout[(size_t)(p0 + row) * 256 + n0 + c4] = v;
    }
}

// K4: out = feat . wB'^T + bias' -> fp32 channel-major [b][n][hw]
__global__ __launch_bounds__(256, 3) void k_out(
    const unsigned short* __restrict__ A, const unsigned short* __restrict__ Wb,
    const float* __restrict__ bias, float* __restrict__ Cout)
{
    __shared__ alignas(16) char smem[32768];
    const int t  = threadIdx.x;
    const int bx = blockIdx.x;
    const int n0 = (bx & 1) * 128;
    const int p0 = (bx >> 1) * 128;

    GEMM_STAGE_AND_MFMA(A, Wb, smem)

    const int mh = (w & 1) * 64, nh = (w >> 1) * 64;
    const int b   = p0 >> 14;
    const int hw0 = p0 & (HW_ - 1);
#pragma unroll
    for (int j = 0; j < 4; ++j) {
        const int   n  = n0 + nh + j * 16 + lr;
        const float bb = bias[n];
#pragma unroll
        for (int i = 0; i < 4; ++i) {
            f32x4_t v = acc[i][j];
            v[0] += bb; v[1] += bb; v[2] += bb; v[3] += bb;
            *(f32x4_t*)&Cout[(size_t)(b * 256 + n) * HW_ + hw0 + mh + i * 16 + lq * 4] = v;
        }
    }
}

// ---------------------------------------------------------------------------
// K3: gather + weighted sum + residual (BN folded into k_out weights).
// 8 channels/lane (uint4 = 16B gathers), 32 lanes per pixel, no coord math.
// ---------------------------------------------------------------------------
__global__ __launch_bounds__(256) void k_sample(
    const unsigned short* __restrict__ proj, const float4* __restrict__ tabW,
    const int4* __restrict__ tabI, unsigned short* __restrict__ feat)
{
    const int t  = threadIdx.x;
    const int w  = t >> 6;
    const int l  = t & 63;
    const int ph = l >> 5;
    const int c0 = (l & 31) * 8;

    const int pbase = blockIdx.x * 16;     // 16384 % 16 == 0: same b for whole block
    const int b = pbase >> 14;
    const unsigned short* projb = proj + (size_t)b * HW_ * 256;

#pragma unroll
    for (int it = 0; it < 2; ++it) {
        const int p = pbase + it * 8 + w * 2 + ph;
        const uint4 rv = *(const uint4*)&proj[(size_t)p * 256 + c0];
        float2 a0 = up2(rv.x), a1 = up2(rv.y), a2 = up2(rv.z), a3 = up2(rv.w);
#pragma unroll
        for (int k = 0; k < 4; ++k) {
            const float4 wv = tabW[(size_t)k * P_ + p];   // broadcast within half-wave
            const int4   ov = tabI[(size_t)k * P_ + p];
            const uint4 g0 = *(const uint4*)&projb[ov.x + c0];
            const uint4 g1 = *(const uint4*)&projb[ov.y + c0];
            const uint4 g2 = *(const uint4*)&projb[ov.z + c0];
            const uint4 g3 = *(const uint4*)&projb[ov.w + c0];
            fma2(a0, wv.x, up2(g0.x)); fma2(a1, wv.x, up2(g0.y));
            fma2(a2, wv.x, up2(g0.z)); fma2(a3, wv.x, up2(g0.w));
            fma2(a0, wv.y, up2(g1.x)); fma2(a1, wv.y, up2(g1.y));
            fma2(a2, wv.y, up2(g1.z)); fma2(a3, wv.y, up2(g1.w));
            fma2(a0, wv.z, up2(g2.x)); fma2(a1, wv.z, up2(g2.y));
            fma2(a2, wv.z, up2(g2.z)); fma2(a3, wv.z, up2(g2.w));
            fma2(a0, wv.w, up2(g3.x)); fma2(a1, wv.w, up2(g3.y));
            fma2(a2, wv.w, up2(g3.z)); fma2(a3, wv.w, up2(g3.w));
        }
        uint4 o;
        o.x = (unsigned)f2bf(a0.x) | ((unsigned)f2bf(a0.y) << 16);
        o.y = (unsigned)f2bf(a1.x) | ((unsigned)f2bf(a1.y) << 16);
        o.z = (unsigned)f2bf(a2.x) | ((unsigned)f2bf(a2.y) << 16);
        o.w = (unsigned)f2bf(a3.x) | ((unsigned)f2bf(a3.y) << 16);
        *(uint4*)&feat[(size_t)p * 256 + c0] = o;
    }
}

extern "C" void kernel_launch(void* const* d_in, const int* in_sizes, int n_in,
                              void* d_out, int out_size, void* d_ws, size_t ws_size,
                              hipStream_t stream)
{
    const float* x      = (const float*)d_in[0];
    const float* conv_w = (const float*)d_in[1];
    const float* conv_b = (const float*)d_in[2];
    const float* off_w  = (const float*)d_in[3];
    const float* off_b  = (const float*)d_in[4];
    const float* wgt_w  = (const float*)d_in[5];
    const float* wgt_b  = (const float*)d_in[6];
    const float* gamma  = (const float*)d_in[7];
    const float* beta   = (const float*)d_in[8];
    const float* rmean  = (const float*)d_in[9];
    const float* rvar   = (const float*)d_in[10];
    const float* out_w  = (const float*)d_in[11];
    const float* out_b  = (const float*)d_in[12];

    char* ws = (char*)d_ws;
    unsigned short* xT   = (unsigned short*)(ws);                      // 64 MiB
    unsigned short* proj = (unsigned short*)(ws + (size_t)67108864);   // 64 MiB
    unsigned short* feat = (unsigned short*)(ws + (size_t)134217728);  // 64 MiB
    float4*         tabW = (float4*)(ws + (size_t)201326592);          // 8 MiB
    int4*           tabI = (int4*)(ws + (size_t)209715200);            // 8 MiB
    unsigned short* wA   = (unsigned short*)(ws + (size_t)218103808);  // 128 KiB
    unsigned short* wB   = (unsigned short*)(ws + (size_t)218234880);  // 128 KiB
    float*          bias2= (float*)(ws + (size_t)218365952);           // 1 KiB

    k_prep  <<<65,         256, 0, stream>>>(conv_w, out_w, gamma, beta, rmean, rvar,
                                             out_b, wA, wB, bias2);
    k_flows <<<P_ / 256,   256, 0, stream>>>(x, off_w, off_b, wgt_w, wgt_b, xT, tabW, tabI);
    k_proj  <<<(P_/128)*2, 256, 0, stream>>>(xT, wA, conv_b, proj);
    k_sample<<<P_ / 16,    256, 0, stream>>>(proj, tabW, tabI, feat);
    k_out   <<<(P_/128)*2, 256, 0, stream>>>(feat, wB, bias2, (float*)d_out);
}

// Round 5
// 392.545 us; speedup vs baseline: 1.1491x; 1.0856x over previous
//
#include <hip/hip_runtime.h>
#include <cstddef>
#include <cstdint>

#define B_    8
#define CIN_  256
#define COUT_ 256
#define K_    4
#define H_    128
#define W_    128
#define HW_   (H_ * W_)    // 16384
#define P_    (B_ * HW_)   // 131072
#define BN_EPS 1e-5f

typedef __attribute__((ext_vector_type(8))) short bf16x8_t;   // 8 bf16 payloads (4 VGPRs)
typedef __attribute__((ext_vector_type(4))) float f32x4_t;

// fp32 -> bf16 payload, round-to-nearest-even
__device__ __forceinline__ unsigned short f2bf(float f) {
    unsigned int u = __float_as_uint(f);
    u += 0x7fffu + ((u >> 16) & 1u);
    return (unsigned short)(u >> 16);
}
// uint holding 2 bf16 -> float2 (2 VALU ops)
__device__ __forceinline__ float2 up2(unsigned int u) {
    return make_float2(__uint_as_float(u << 16), __uint_as_float(u & 0xffff0000u));
}
__device__ __forceinline__ void fma2(float2& d, float s, float2 v) {
    d.x = fmaf(s, v.x, d.x);
    d.y = fmaf(s, v.y, d.y);
}

// async global->LDS, 16B per lane; lds base must be wave-uniform (HW adds lane*16)
#define GL2LDS(g, l)                                                                     \
    __builtin_amdgcn_global_load_lds((const __attribute__((address_space(1))) void*)(g), \
                                     (__attribute__((address_space(3))) void*)(l), 16, 0, 0)

// ---------------------------------------------------------------------------
// K0: prep. Blocks 0..63: cast conv_w to bf16. Block 64: fold BN into out_w.
// Block 65: build wB2[16][256] bf16 = [off_w(8 rows); wgt_w(4 rows); zeros(4)]
// (flattened j = k*2+xy for offsets, 8+k for logits) -- the flows-GEMM B.
// ---------------------------------------------------------------------------
__global__ __launch_bounds__(256) void k_prep(
    const float* __restrict__ conv_w, const float* __restrict__ out_w,
    const float* __restrict__ gamma, const float* __restrict__ beta,
    const float* __restrict__ rmean, const float* __restrict__ rvar,
    const float* __restrict__ out_b, const float* __restrict__ off_w,
    const float* __restrict__ wgt_w,
    unsigned short* __restrict__ wA, unsigned short* __restrict__ wB,
    float* __restrict__ bias2, unsigned short* __restrict__ wB2)
{
    const int t = threadIdx.x;
    if (blockIdx.x < 64) {
        const int i = (blockIdx.x * 256 + t) * 4;
        float4 a = *(const float4*)&conv_w[i];
        uint2 pa;
        pa.x = (unsigned)f2bf(a.x) | ((unsigned)f2bf(a.y) << 16);
        pa.y = (unsigned)f2bf(a.z) | ((unsigned)f2bf(a.w) << 16);
        *(uint2*)&wA[i] = pa;
    } else if (blockIdx.x == 64) {
        __shared__ float sinv[256], sd[256];
        const float iv = gamma[t] * rsqrtf(rvar[t] + BN_EPS);
        sinv[t] = iv;
        sd[t]   = beta[t] - rmean[t] * iv;
        __syncthreads();
        float acc = out_b[t];
        for (int c = 0; c < 256; c += 4) {
            const float4 wv = *(const float4*)&out_w[t * 256 + c];
            acc += sd[c] * wv.x + sd[c + 1] * wv.y + sd[c + 2] * wv.z + sd[c + 3] * wv.w;
            uint2 p;
            p.x = (unsigned)f2bf(wv.x * sinv[c])     | ((unsigned)f2bf(wv.y * sinv[c + 1]) << 16);
            p.y = (unsigned)f2bf(wv.z * sinv[c + 2]) | ((unsigned)f2bf(wv.w * sinv[c + 3]) << 16);
            *(uint2*)&wB[t * 256 + c] = p;
        }
        bias2[t] = acc;
    } else {
        // off_w is (K,2,CIN) row-major: flat row j = k*2+xy at off_w[j*256 + c]
        for (int j = 0; j < 16; ++j) {
            float v = 0.f;
            if (j < 8)       v = off_w[j * 256 + t];
            else if (j < 12) v = wgt_w[(j - 8) * 256 + t];
            wB2[j * 256 + t] = f2bf(v);
        }
    }
}

// ---------------------------------------------------------------------------
// K1 (fused flows+proj): reads x ONCE. Per block: 128 px, full 256 out-ch.
//  - A-step [128 px][64 cin] bf16 staged in LDS from strided fp32 x reads,
//    XOR-swizzled (byte ^= (px&7)<<4) -> ds_read_b128 fragments ~2-way free
//  - proj GEMM: 8 waves (2m x 4n), acc[4][4], Bs via global_load_lds
//  - flows GEMM: same A-tile vs wB2[16][256] -> 2 extra MFMA/wave/K-step
//  - next-K x prefetched to regs before each barrier (latency under MFMA)
//  - epilogue: tabs tail (t<128) + proj bf16 via full-line LDS roundtrip
// Eliminates the xT buffer entirely (-64MB write, -128MB read vs r4).
// ---------------------------------------------------------------------------
__global__ __launch_bounds__(512, 2) void k_fproj(
    const float* __restrict__ x, const unsigned short* __restrict__ wA,
    const unsigned short* __restrict__ wB2, const float* __restrict__ conv_b,
    const float* __restrict__ off_b, const float* __restrict__ wgt_b,
    unsigned short* __restrict__ proj, float4* __restrict__ tabW,
    int4* __restrict__ tabI)
{
    __shared__ alignas(16) char smem[57856];
    char*           AsB  = smem;                          // [128 px][128 B] swz, 16 KB
    char*           Bs   = smem + 16384;                  // 32 x 1KB frag tiles, 32 KB
    float*          fbuf = (float*)(smem + 49152);        // [128][17] fp32, 8.7 KB
    unsigned short* ep   = (unsigned short*)smem;         // [128][132] u16 (reuse)

    const int t   = threadIdx.x;
    const int w   = t >> 6;
    const int l   = t & 63;
    const int lr  = l & 15;
    const int lq  = l >> 4;
    const int wm2 = w & 1;           // m-half (64 px)
    const int wn4 = w >> 1;          // n-quarter (64 ch)
    const int chg = t & 15;          // staging: 16 ch-groups of 4
    const int pxg = t >> 4;          // staging: 32 px-groups of 4
    const int p0  = blockIdx.x * 128;
    const float* xb = x + (size_t)(p0 >> 14) * (256 * HW_) + (p0 & (HW_ - 1)) + pxg * 4;

    f32x4_t acc[4][4];
#pragma unroll
    for (int i = 0; i < 4; ++i)
#pragma unroll
        for (int j = 0; j < 4; ++j) acc[i][j] = (f32x4_t){0.f, 0.f, 0.f, 0.f};
    f32x4_t acc2 = (f32x4_t){0.f, 0.f, 0.f, 0.f};

    float4 f[4], fn[4];
#pragma unroll
    for (int i = 0; i < 4; ++i)
        f[i] = *(const float4*)&xb[(size_t)(chg * 4 + i) * HW_];

    for (int ks = 0; ks < 4; ++ks) {
        // pack + transpose-write A-step: per px, 4 consecutive ch -> uint2 (b64)
#pragma unroll
        for (int o = 0; o < 4; ++o) {
            const int px = pxg * 4 + o;
            const float v0 = (o == 0) ? f[0].x : (o == 1) ? f[0].y : (o == 2) ? f[0].z : f[0].w;
            const float v1 = (o == 0) ? f[1].x : (o == 1) ? f[1].y : (o == 2) ? f[1].z : f[1].w;
            const float v2 = (o == 0) ? f[2].x : (o == 1) ? f[2].y : (o == 2) ? f[2].z : f[2].w;
            const float v3 = (o == 0) ? f[3].x : (o == 1) ? f[3].y : (o == 2) ? f[3].z : f[3].w;
            uint2 u;
            u.x = (unsigned)f2bf(v0) | ((unsigned)f2bf(v1) << 16);
            u.y = (unsigned)f2bf(v2) | ((unsigned)f2bf(v3) << 16);
            *(uint2*)(AsB + ((px * 128 + chg * 8) ^ ((px & 7) << 4))) = u;
        }
        // stage Bs (wA rows for all 256 out-ch, this K-step): 4 GL2LDS per wave
#pragma unroll
        for (int s = 0; s < 4; ++s) {
            const int idx = w * 4 + s;                    // kc = idx>>4, nt = idx&15
            const unsigned short* g = wA + (size_t)((idx & 15) * 16 + lr) * 256
                                      + ks * 64 + (idx >> 4) * 32 + lq * 8;
            GL2LDS(g, Bs + idx * 1024);
        }
        // prefetch next K-step's x into registers (latency hides under MFMA+barrier)
        if (ks < 3) {
#pragma unroll
            for (int i = 0; i < 4; ++i)
                fn[i] = *(const float4*)&xb[(size_t)((ks + 1) * 64 + chg * 4 + i) * HW_];
        }
        __syncthreads();
        // flows MFMA: m-tile = wave id, n = 16 (12 used)
        {
            const int px = w * 16 + lr;
#pragma unroll
            for (int kc = 0; kc < 2; ++kc) {
                const bf16x8_t a2 = *(const bf16x8_t*)(AsB +
                    ((px * 128 + kc * 64 + lq * 16) ^ ((px & 7) << 4)));
                const bf16x8_t b2 = *(const bf16x8_t*)&wB2[lr * 256 + ks * 64 + kc * 32 + lq * 8];
                acc2 = __builtin_amdgcn_mfma_f32_16x16x32_bf16(a2, b2, acc2, 0, 0, 0);
            }
        }
        // proj MFMA: wave tile 64px x 64ch
#pragma unroll
        for (int kc = 0; kc < 2; ++kc) {
            bf16x8_t af[4], bfr[4];
#pragma unroll
            for (int i = 0; i < 4; ++i) {
                const int px = (wm2 * 4 + i) * 16 + lr;
                af[i] = *(const bf16x8_t*)(AsB +
                    ((px * 128 + kc * 64 + lq * 16) ^ ((px & 7) << 4)));
            }
#pragma unroll
            for (int j = 0; j < 4; ++j)
                bfr[j] = *(const bf16x8_t*)(Bs + (kc * 16 + wn4 * 4 + j) * 1024 + l * 16);
#pragma unroll
            for (int i = 0; i < 4; ++i)
#pragma unroll
                for (int j = 0; j < 4; ++j)
                    acc[i][j] = __builtin_amdgcn_mfma_f32_16x16x32_bf16(af[i], bfr[j],
                                                                        acc[i][j], 0, 0, 0);
        }
        __syncthreads();
        if (ks < 3) {
#pragma unroll
            for (int i = 0; i < 4; ++i) f[i] = fn[i];
        }
    }

    // flows C -> fbuf: lane holds col=j (lane&15), rows px = w*16 + lq*4 + r
#pragma unroll
    for (int r = 0; r < 4; ++r)
        fbuf[(w * 16 + lq * 4 + r) * 17 + lr] = acc2[r];
    __syncthreads();

    // tabs tail: one thread per pixel (waves 0,1)
    if (t < 128) {
        const int p = p0 + t;
        float a[12];
#pragma unroll
        for (int j = 0; j < 12; ++j) a[j] = fbuf[t * 17 + j];

        const int hw = p & (HW_ - 1);
        const int wx = hw & (W_ - 1);
        const int hy = hw >> 7;
        float lg[4];
#pragma unroll
        for (int k = 0; k < 4; ++k) lg[k] = a[8 + k] + wgt_b[k];
        const float m  = fmaxf(fmaxf(lg[0], lg[1]), fmaxf(lg[2], lg[3]));
        const float e0 = __expf(lg[0] - m), e1 = __expf(lg[1] - m);
        const float e2 = __expf(lg[2] - m), e3 = __expf(lg[3] - m);
        const float sinv = 1.f / (e0 + e1 + e2 + e3);
        const float wk[4] = {e0 * sinv, e1 * sinv, e2 * sinv, e3 * sinv};

#pragma unroll
        for (int k = 0; k < 4; ++k) {
            const float sx = (float)wx + a[k * 2 + 0] + off_b[k * 2 + 0];
            const float sy = (float)hy + a[k * 2 + 1] + off_b[k * 2 + 1];
            const float x0f = floorf(sx), y0f = floorf(sy);
            const float fx = sx - x0f, fy = sy - y0f;
            const float vx0 = (x0f >= 0.f  && x0f <= (float)(W_ - 1)) ? 1.f : 0.f;
            const float vx1 = (x0f >= -1.f && x0f <= (float)(W_ - 2)) ? 1.f : 0.f;
            const float vy0 = (y0f >= 0.f  && y0f <= (float)(H_ - 1)) ? 1.f : 0.f;
            const float vy1 = (y0f >= -1.f && y0f <= (float)(H_ - 2)) ? 1.f : 0.f;
            const int x0 = (int)x0f, y0 = (int)y0f;
            const int cx0 = min(max(x0, 0), W_ - 1);
            const int cx1 = min(max(x0 + 1, 0), W_ - 1);
            const int cy0 = min(max(y0, 0), H_ - 1);
            const int cy1 = min(max(y0 + 1, 0), H_ - 1);
            float4 wv;
            wv.x = (1.f - fx) * (1.f - fy) * wk[k] * vx0 * vy0;
            wv.y = fx * (1.f - fy) * wk[k] * vx1 * vy0;
            wv.z = (1.f - fx) * fy * wk[k] * vx0 * vy1;
            wv.w = fx * fy * wk[k] * vx1 * vy1;
            int4 ov;
            ov.x = (cy0 * W_ + cx0) * 256;
            ov.y = (cy0 * W_ + cx1) * 256;
            ov.z = (cy1 * W_ + cx0) * 256;
            ov.w = (cy1 * W_ + cx1) * 256;
            tabW[(size_t)k * P_ + p] = wv;
            tabI[(size_t)k * P_ + p] = ov;
        }
    }

    // proj epilogue: two 128-col halves through [128][132] LDS, full-line stores
    for (int h = 0; h < 2; ++h) {
        if ((wn4 >> 1) == h) {
#pragma unroll
            for (int j = 0; j < 4; ++j) {
                const int ncol = wn4 * 64 + j * 16 + lr;
                const float bv = conv_b[ncol];
                const int cl = (wn4 & 1) * 64 + j * 16 + lr;
#pragma unroll
                for (int i = 0; i < 4; ++i)
#pragma unroll
                    for (int r = 0; r < 4; ++r) {
                        const int row = (wm2 * 4 + i) * 16 + lq * 4 + r;
                        ep[row * 132 + cl] = f2bf(acc[i][j][r] + bv);
                    }
            }
        }
        __syncthreads();
#pragma unroll
        for (int pass = 0; pass < 8; ++pass) {
            const int row = pass * 16 + (t >> 5);
            const int c4  = (t & 31) * 4;
            const uint2 v = *(const uint2*)&ep[row * 132 + c4];
            *(uint2*)&proj[(size_t)(p0 + row) * 256 + h * 128 + c4] = v;
        }
        __syncthreads();
    }
}

// ---------------------------------------------------------------------------
// GEMM core (k_out): C[m=px][n=o] = sum_c A[px][c]*W[o][c]
// 128x128 tile, BK=64, fragment-major LDS staged via global_load_lds(16B).
// ---------------------------------------------------------------------------
#define GEMM_STAGE_AND_MFMA(A_, W_ptr_, smem_)                                              \
    char* As = smem_;                                                                       \
    char* Bs = smem_ + 16384;                                                               \
    const int w  = t >> 6;                                                                  \
    const int l  = t & 63;                                                                  \
    const int lr = l & 15;                                                                  \
    const int lq = l >> 4;                                                                  \
    f32x4_t acc[4][4];                                                                      \
    _Pragma("unroll") for (int i = 0; i < 4; ++i)                                           \
        _Pragma("unroll") for (int j = 0; j < 4; ++j)                                       \
            acc[i][j] = (f32x4_t){0.f, 0.f, 0.f, 0.f};                                      \
    const int wm = (w & 1) * 4;                                                             \
    const int wn = (w >> 1) * 4;                                                            \
    _Pragma("unroll") for (int ks = 0; ks < 4; ++ks) {                                      \
        const int k0 = ks * 64;                                                             \
        __syncthreads();                                                                    \
        _Pragma("unroll") for (int i = 0; i < 2; ++i) {                                     \
            const int mt = 2 * w + i;                                                       \
            _Pragma("unroll") for (int kc = 0; kc < 2; ++kc) {                              \
                const unsigned short* g =                                                   \
                    A_ + (size_t)(p0 + mt * 16 + lr) * 256 + k0 + kc * 32 + lq * 8;         \
                GL2LDS(g, As + (kc * 8 + mt) * 1024);                                       \
            }                                                                               \
        }                                                                                   \
        _Pragma("unroll") for (int i = 0; i < 2; ++i) {                                     \
            const int nt = 2 * w + i;                                                       \
            _Pragma("unroll") for (int kc = 0; kc < 2; ++kc) {                              \
                const unsigned short* g =                                                   \
                    W_ptr_ + (size_t)(n0 + nt * 16 + lr) * 256 + k0 + kc * 32 + lq * 8;     \
                GL2LDS(g, Bs + (kc * 8 + nt) * 1024);                                       \
            }                                                                               \
        }                                                                                   \
        __syncthreads();                                                                    \
        _Pragma("unroll") for (int kc = 0; kc < 2; ++kc) {                                  \
            bf16x8_t af[4], bfr[4];                                                         \
            _Pragma("unroll") for (int i = 0; i < 4; ++i)                                   \
                af[i] = *(const bf16x8_t*)(As + (kc * 8 + wm + i) * 1024 + l * 16);         \
            _Pragma("unroll") for (int j = 0; j < 4; ++j)                                   \
                bfr[j] = *(const bf16x8_t*)(Bs + (kc * 8 + wn + j) * 1024 + l * 16);        \
            _Pragma("unroll") for (int i = 0; i < 4; ++i)                                   \
                _Pragma("unroll") for (int j = 0; j < 4; ++j)                               \
                    acc[i][j] =                                                             \
                        __builtin_amdgcn_mfma_f32_16x16x32_bf16(af[i], bfr[j], acc[i][j],   \
                                                                0, 0, 0);                   \
        }                                                                                   \
    }

// K4: out = feat . wB'^T + bias' -> fp32 channel-major [b][n][hw]
__global__ __launch_bounds__(256, 3) void k_out(
    const unsigned short* __restrict__ A, const unsigned short* __restrict__ Wb,
    const float* __restrict__ bias, float* __restrict__ Cout)
{
    __shared__ alignas(16) char smem[32768];
    const int t  = threadIdx.x;
    const int bx = blockIdx.x;
    const int n0 = (bx & 1) * 128;
    const int p0 = (bx >> 1) * 128;

    GEMM_STAGE_AND_MFMA(A, Wb, smem)

    const int mh = (w & 1) * 64, nh = (w >> 1) * 64;
    const int b   = p0 >> 14;
    const int hw0 = p0 & (HW_ - 1);
#pragma unroll
    for (int j = 0; j < 4; ++j) {
        const int   n  = n0 + nh + j * 16 + lr;
        const float bb = bias[n];
#pragma unroll
        for (int i = 0; i < 4; ++i) {
            f32x4_t v = acc[i][j];
            v[0] += bb; v[1] += bb; v[2] += bb; v[3] += bb;
            *(f32x4_t*)&Cout[(size_t)(b * 256 + n) * HW_ + hw0 + mh + i * 16 + lq * 4] = v;
        }
    }
}

// ---------------------------------------------------------------------------
// K3: gather + weighted sum + residual (BN folded into k_out weights).
// 8 channels/lane (uint4 = 16B gathers), 32 lanes per pixel, no coord math.
// ---------------------------------------------------------------------------
__global__ __launch_bounds__(256) void k_sample(
    const unsigned short* __restrict__ proj, const float4* __restrict__ tabW,
    const int4* __restrict__ tabI, unsigned short* __restrict__ feat)
{
    const int t  = threadIdx.x;
    const int w  = t >> 6;
    const int l  = t & 63;
    const int ph = l >> 5;
    const int c0 = (l & 31) * 8;

    const int pbase = blockIdx.x * 16;     // 16384 % 16 == 0: same b for whole block
    const int b = pbase >> 14;
    const unsigned short* projb = proj + (size_t)b * HW_ * 256;

#pragma unroll
    for (int it = 0; it < 2; ++it) {
        const int p = pbase + it * 8 + w * 2 + ph;
        const uint4 rv = *(const uint4*)&proj[(size_t)p * 256 + c0];
        float2 a0 = up2(rv.x), a1 = up2(rv.y), a2 = up2(rv.z), a3 = up2(rv.w);
#pragma unroll
        for (int k = 0; k < 4; ++k) {
            const float4 wv = tabW[(size_t)k * P_ + p];   // broadcast within half-wave
            const int4   ov = tabI[(size_t)k * P_ + p];
            const uint4 g0 = *(const uint4*)&projb[ov.x + c0];
            const uint4 g1 = *(const uint4*)&projb[ov.y + c0];
            const uint4 g2 = *(const uint4*)&projb[ov.z + c0];
            const uint4 g3 = *(const uint4*)&projb[ov.w + c0];
            fma2(a0, wv.x, up2(g0.x)); fma2(a1, wv.x, up2(g0.y));
            fma2(a2, wv.x, up2(g0.z)); fma2(a3, wv.x, up2(g0.w));
            fma2(a0, wv.y, up2(g1.x)); fma2(a1, wv.y, up2(g1.y));
            fma2(a2, wv.y, up2(g1.z)); fma2(a3, wv.y, up2(g1.w));
            fma2(a0, wv.z, up2(g2.x)); fma2(a1, wv.z, up2(g2.y));
            fma2(a2, wv.z, up2(g2.z)); fma2(a3, wv.z, up2(g2.w));
            fma2(a0, wv.w, up2(g3.x)); fma2(a1, wv.w, up2(g3.y));
            fma2(a2, wv.w, up2(g3.z)); fma2(a3, wv.w, up2(g3.w));
        }
        uint4 o;
        o.x = (unsigned)f2bf(a0.x) | ((unsigned)f2bf(a0.y) << 16);
        o.y = (unsigned)f2bf(a1.x) | ((unsigned)f2bf(a1.y) << 16);
        o.z = (unsigned)f2bf(a2.x) | ((unsigned)f2bf(a2.y) << 16);
        o.w = (unsigned)f2bf(a3.x) | ((unsigned)f2bf(a3.y) << 16);
        *(uint4*)&feat[(size_t)p * 256 + c0] = o;
    }
}

extern "C" void kernel_launch(void* const* d_in, const int* in_sizes, int n_in,
                              void* d_out, int out_size, void* d_ws, size_t ws_size,
                              hipStream_t stream)
{
    const float* x      = (const float*)d_in[0];
    const float* conv_w = (const float*)d_in[1];
    const float* conv_b = (const float*)d_in[2];
    const float* off_w  = (const float*)d_in[3];
    const float* off_b  = (const float*)d_in[4];
    const float* wgt_w  = (const float*)d_in[5];
    const float* wgt_b  = (const float*)d_in[6];
    const float* gamma  = (const float*)d_in[7];
    const float* beta   = (const float*)d_in[8];
    const float* rmean  = (const float*)d_in[9];
    const float* rvar   = (const float*)d_in[10];
    const float* out_w  = (const float*)d_in[11];
    const float* out_b  = (const float*)d_in[12];

    char* ws = (char*)d_ws;
    unsigned short* wB2  = (unsigned short*)(ws);                      // 8 KiB (xT region freed)
    unsigned short* proj = (unsigned short*)(ws + (size_t)67108864);   // 64 MiB
    unsigned short* feat = (unsigned short*)(ws + (size_t)134217728);  // 64 MiB
    float4*         tabW = (float4*)(ws + (size_t)201326592);          // 8 MiB
    int4*           tabI = (int4*)(ws + (size_t)209715200);            // 8 MiB
    unsigned short* wA   = (unsigned short*)(ws + (size_t)218103808);  // 128 KiB
    unsigned short* wB   = (unsigned short*)(ws + (size_t)218234880);  // 128 KiB
    float*          bias2= (float*)(ws + (size_t)218365952);           // 1 KiB

    k_prep  <<<66,         256, 0, stream>>>(conv_w, out_w, gamma, beta, rmean, rvar,
                                             out_b, off_w, wgt_w, wA, wB, bias2, wB2);
    k_fproj <<<P_ / 128,   512, 0, stream>>>(x, wA, wB2, conv_b, off_b, wgt_b,
                                             proj, tabW, tabI);
    k_sample<<<P_ / 16,    256, 0, stream>>>(proj, tabW, tabI, feat);
    k_out   <<<(P_/128)*2, 256, 0, stream>>>(feat, wB, bias2, (float*)d_out);
}